// Round 12
// baseline (441.962 us; speedup 1.0000x reference)
//
#include <hip/hip_runtime.h>
#include <math.h>

#define B_SZ 4
#define IN_F 32
#define H1_F 32
#define H2_F 30
#define TPW 16   // tiles per wave in edge kernel
#define HREP 16  // histogram replicas (atomic hot-line chain reduction)

typedef unsigned int uint;
typedef unsigned short ushort;
typedef unsigned long long ull;
typedef __attribute__((ext_vector_type(8))) short bf16x8;
typedef __attribute__((ext_vector_type(4))) float f32x4;

__device__ __forceinline__ float fastrcp(float x) {
#if __has_builtin(__builtin_amdgcn_rcpf)
    return __builtin_amdgcn_rcpf(x);
#else
    return 1.f / x;
#endif
}
__device__ __forceinline__ float sigmoidf_(float x) {
    return fastrcp(1.f + __expf(-x));
}

__device__ __forceinline__ ushort f2bf(float f) {
    uint u = __float_as_uint(f);
    return (ushort)((u + 0x7FFFu + ((u >> 16) & 1u)) >> 16);  // RNE
}
__device__ __forceinline__ float bf2f(ushort v) { return __uint_as_float(((uint)v) << 16); }
__device__ __forceinline__ uint pk2(float a, float b) {
    return (uint)f2bf(a) | ((uint)f2bf(b) << 16);
}
// HW packed f32->bf16 (RNE), 1 instruction per pair.
__device__ __forceinline__ uint pk2f(float a, float b) {
    uint r;
    asm("v_cvt_pk_bf16_f32 %0, %1, %2" : "=v"(r) : "v"(a), "v"(b));
    return r;
}

union Frag { bf16x8 v; ushort us[8]; uint u[4]; };

// ---------------------------------------------------------------------------
// MERGED: ea stats (per-block partials) + degree histogram (HREP-replicated,
// fire-and-forget atomics) + x f32->bf16 conversion.
// ---------------------------------------------------------------------------
__global__ void __launch_bounds__(256) stats_xcvt_kernel(
    const float* __restrict__ ea, const int* __restrict__ ei,
    const float* __restrict__ x, float2* __restrict__ psums,
    int* __restrict__ cnt, ushort* __restrict__ xb,
    int E, int N, long long n8) {
    long long i = (long long)blockIdx.x * 256 + threadIdx.x;
    if (i < n8) {
        const float4* p = (const float4*)(x + i * 8);
        float4 v0 = p[0], v1 = p[1];
        uint4 o;
        o.x = pk2f(v0.x, v0.y); o.y = pk2f(v0.z, v0.w);
        o.z = pk2f(v1.x, v1.y); o.w = pk2f(v1.z, v1.w);
        *(uint4*)(xb + i * 8) = o;
    }
    int e = blockIdx.x * 256 + threadIdx.x;
    int* myc = cnt + (size_t)(blockIdx.x & (HREP - 1)) * N;
    float a = (e < E) ? ea[e] : 0.f;
    if (e < E) {
        atomicAdd(&myc[ei[E + e]], 1);
        atomicAdd(&myc[ei[e]], 1);
    }
    float v = a, v2 = a * a;
    for (int off = 32; off > 0; off >>= 1) {
        v  += __shfl_down(v, off);
        v2 += __shfl_down(v2, off);
    }
    __shared__ float s1[4], s2[4];
    int wid = threadIdx.x >> 6, lane = threadIdx.x & 63;
    if (lane == 0) { s1[wid] = v; s2[wid] = v2; }
    __syncthreads();
    if (threadIdx.x == 0) {
        float2 p;
        p.x = s1[0] + s1[1] + s1[2] + s1[3];
        p.y = s2[0] + s2[1] + s2[2] + s2[3];
        psums[blockIdx.x] = p;
    }
}

// single-block reduction of per-block partials -> sums[0..1]
__global__ void __launch_bounds__(256) sums_reduce_kernel(
    const float2* __restrict__ psums, float* __restrict__ sums, int nblk) {
    float v = 0.f, v2 = 0.f;
    for (int i = threadIdx.x; i < nblk; i += 256) {
        float2 p = psums[i];
        v += p.x; v2 += p.y;
    }
    for (int off = 32; off > 0; off >>= 1) {
        v  += __shfl_down(v, off);
        v2 += __shfl_down(v2, off);
    }
    __shared__ float s1[4], s2[4];
    int wid = threadIdx.x >> 6, lane = threadIdx.x & 63;
    if (lane == 0) { s1[wid] = v; s2[wid] = v2; }
    __syncthreads();
    if (threadIdx.x == 0) {
        sums[0] = s1[0] + s1[1] + s1[2] + s1[3];
        sums[1] = s2[0] + s2[1] + s2[2] + s2[3];
    }
}

// ---------------------------------------------------------------------------
// 3-phase multi-block exclusive scan; phase 1 sums the HREP replicas.
// ---------------------------------------------------------------------------
__global__ void __launch_bounds__(256) scan1_kernel(const int* __restrict__ cnt,
                                                    int* __restrict__ offs,
                                                    int* __restrict__ bsum, int n) {
    __shared__ int wtot[4];
    int base = blockIdx.x * 1024 + threadIdx.x * 4;
    int4 v = {0, 0, 0, 0};
    if (base + 3 < n) {
#pragma unroll
        for (int r = 0; r < HREP; r++) {
            int4 t = *(const int4*)(cnt + (size_t)r * n + base);
            v.x += t.x; v.y += t.y; v.z += t.z; v.w += t.w;
        }
    } else {
        for (int r = 0; r < HREP; r++) {
            const int* c = cnt + (size_t)r * n;
            if (base < n)     v.x += c[base];
            if (base + 1 < n) v.y += c[base + 1];
            if (base + 2 < n) v.z += c[base + 2];
            if (base + 3 < n) v.w += c[base + 3];
        }
    }
    int s = v.x + v.y + v.z + v.w;
    int incl = s;
    int lane = threadIdx.x & 63;
    for (int d = 1; d < 64; d <<= 1) {
        int t = __shfl_up(incl, d);
        if (lane >= d) incl += t;
    }
    int wid = threadIdx.x >> 6;
    if (lane == 63) wtot[wid] = incl;
    __syncthreads();
    int woff = 0, tot = 0;
#pragma unroll
    for (int w = 0; w < 4; w++) {
        int t = wtot[w];
        if (w < wid) woff += t;
        tot += t;
    }
    int excl = woff + incl - s;
    int4 o;
    o.x = excl; o.y = excl + v.x; o.z = o.y + v.y; o.w = o.z + v.z;
    if (base + 3 < n) *(int4*)(offs + base) = o;
    else {
        if (base < n)     offs[base] = o.x;
        if (base + 1 < n) offs[base + 1] = o.y;
        if (base + 2 < n) offs[base + 2] = o.z;
        if (base + 3 < n) offs[base + 3] = o.w;
    }
    if (threadIdx.x == 0) bsum[blockIdx.x] = tot;
}

__global__ void scan2_kernel(int* __restrict__ bsum, int* __restrict__ offs,
                             int nb, int n) {
    int lane = threadIdx.x;
    if (nb <= 64) {
        int v = (lane < nb) ? bsum[lane] : 0;
        int incl = v;
        for (int d = 1; d < 64; d <<= 1) {
            int t = __shfl_up(incl, d);
            if (lane >= d) incl += t;
        }
        if (lane < nb) bsum[lane] = incl - v;
        if (lane == 63) offs[n] = incl;
    } else if (lane == 0) {
        int run = 0;
        for (int i = 0; i < nb; i++) { int t = bsum[i]; bsum[i] = run; run += t; }
        offs[n] = run;
    }
}

__global__ void __launch_bounds__(256) scan3_kernel(int* __restrict__ offs,
                                                    int* __restrict__ cursor,
                                                    const int* __restrict__ bsum, int n) {
    int base = blockIdx.x * 1024 + threadIdx.x * 4;
    int add = bsum[blockIdx.x];
    if (base + 3 < n) {
        int4 v = *(const int4*)(offs + base);
        v.x += add; v.y += add; v.z += add; v.w += add;
        *(int4*)(offs + base) = v;
        *(int4*)(cursor + base) = v;
    } else {
        for (int k = 0; k < 4; k++) {
            int i = base + k;
            if (i < n) { int v = offs[i] + add; offs[i] = v; cursor[i] = v; }
        }
    }
}

// ---------------------------------------------------------------------------
// BATCH-MAJOR edge MLP, SPLIT-DEPTH PIPELINE (r11: meta 2 ahead, xb 1 ahead,
// claims via __shfl). NEW (r12): h is stored as BATCH-MAJOR PLANES
// h[b][e][32] bf16 (64 B per (b,e) row) -- each block's write stream is now
// perfectly CONTIGUOUS 64 B x consecutive edges instead of 64 B at stride
// 256 B. Shrinks the active L2 write window 4x (less xb eviction; r11's
// residual 257 MB fetch) and gives DRAM dense bursts. Gather traffic is
// unchanged: it already read 4 separate 64 B lines per slot visit.
// Batch-major grid (r10): blocks [b*bpb,(b+1)*bpb) share one 3.2 MB xb
// slice per XCD L2. Claims: prologue claims tile0, iter tix claims
// tile0+tix+1 -> each (edge,side) exactly once.
// ---------------------------------------------------------------------------
__global__ void __launch_bounds__(256) edge_mlp_e4(
    const ushort* __restrict__ xb,
    const int* __restrict__ ei, const float* __restrict__ ea,
    const float* __restrict__ W1, const float* __restrict__ b1,
    const float* __restrict__ W2, const float* __restrict__ b2,
    const float* __restrict__ sums, int* __restrict__ cursor,
    int* __restrict__ list, ushort* __restrict__ h,
    int E, int N, int tiles, int bpb) {
    __shared__ ushort __attribute__((aligned(16))) hbuf[4][16 * 40];
    int w = threadIdx.x >> 6;
    int lane = threadIdx.x & 63;
    int n16 = lane & 15;             // edge-local index within tile
    int q = lane >> 4;

    int b   = blockIdx.x / bpb;      // batch (batch-major grid)
    int blk = blockIdx.x % bpb;

    // weight fragments as operand A (= W^T)
    Frag w1f[2][2];
#pragma unroll
    for (int t = 0; t < 2; t++)
#pragma unroll
        for (int s = 0; s < 2; s++)
#pragma unroll
            for (int j = 0; j < 4; j++) {
                int k0 = 32 * s + q * 8 + 2 * j;
                w1f[t][s].u[j] = pk2(W1[(size_t)k0 * 32 + 16 * t + n16],
                                     W1[(size_t)(k0 + 1) * 32 + 16 * t + n16]);
            }
    Frag w2f[2];
#pragma unroll
    for (int t = 0; t < 2; t++) {
        int m = 16 * t + n16;
#pragma unroll
        for (int j = 0; j < 4; j++) {
            int k0 = q * 8 + 2 * j;
            float a = (m < H2_F) ? W2[(size_t)k0 * H2_F + m] : 0.f;
            float d = (m < H2_F) ? W2[(size_t)(k0 + 1) * H2_F + m] : 0.f;
            w2f[t].u[j] = pk2(a, d);
        }
    }
    float b1q[2][4], w1Lq[2][4], b2q[2][4];
#pragma unroll
    for (int t = 0; t < 2; t++)
#pragma unroll
        for (int r = 0; r < 4; r++) {
            int col = 16 * t + q * 4 + r;
            b1q[t][r]  = b1[col];
            w1Lq[t][r] = W1[(size_t)64 * 32 + col];
            b2q[t][r]  = (col < H2_F) ? b2[col] : 0.f;
        }

    float mean = sums[0] / (float)E;
    float var = (sums[1] - (float)E * mean * mean) / (float)(E - 1);
    float istd = rsqrtf(var);

    int gw = blk * 4 + w;
    int tile0 = gw * TPW;
    if (tile0 >= tiles) return;
    const ushort* xbB_ = xb + (size_t)b * N * IN_F;
    uint* hplane = (uint*)h + (size_t)b * E * 16;   // batch-major plane, 16 uints/edge

    // slot-claim lane mapping: lanes 0..7 -> el = 4*(lane>>1)+b, side = lane&1
    int clm_el = 4 * (lane >> 1) + b;
    int clm_side = lane & 1;

    // ---- pipeline state: meta A = tile t, meta B = tile t+1; frags = tile t
    int sA, tA; float eA_; bool vA;
    int sB = 0, tB = 0; float eB_ = 0.f; bool vB = false;
    Frag a0, a1;

    {
        int e0 = tile0 * 16 + n16; vA = e0 < E; int c = vA ? e0 : E - 1;
        sA = ei[c]; tA = ei[E + c]; eA_ = (ea[c] - mean) * istd;
    }
    if (TPW > 1 && tile0 + 1 < tiles) {
        int e1 = (tile0 + 1) * 16 + n16; vB = e1 < E; int c = vB ? e1 : E - 1;
        sB = ei[c]; tB = ei[E + c]; eB_ = (ea[c] - mean) * istd;
    }
    *(uint4*)&a0.u[0] = *(const uint4*)(xbB_ + (size_t)sA * IN_F + q * 8);
    *(uint4*)&a1.u[0] = *(const uint4*)(xbB_ + (size_t)tA * IN_F + q * 8);
    {
        int nodeS = __shfl(sA, clm_el), nodeT = __shfl(tA, clm_el);
        int eS = tile0 * 16 + clm_el;
        if (lane < 8 && eS < E) {
            int node = clm_side ? nodeS : nodeT;
            int s = atomicAdd(&cursor[node], 1);
            __builtin_nontemporal_store(eS | (int)(((uint)clm_side) << 31), &list[s]);
        }
    }

    for (int tix = 0; tix < TPW; ++tix) {
        int tile = tile0 + tix;
        if (tile >= tiles) break;

        // (1) meta prefetch for tile+2 (independent loads)
        int sC = 0, tC = 0; float eC_ = 0.f; bool vC = false;
        if (tix + 2 < TPW && tile + 2 < tiles) {
            int e2 = (tile + 2) * 16 + n16; vC = e2 < E; int c = vC ? e2 : E - 1;
            sC = ei[c]; tC = ei[E + c]; eC_ = (ea[c] - mean) * istd;
        }
        // (2) xb prefetch for tile+1 (meta B resident for a full iteration)
        Frag b0, b1f;
        b0.u[0] = b0.u[1] = b0.u[2] = b0.u[3] = 0; b1f = b0;
        bool hn = (tix + 1 < TPW) && (tile + 1 < tiles);
        if (hn) {
            *(uint4*)&b0.u[0]  = *(const uint4*)(xbB_ + (size_t)sB * IN_F + q * 8);
            *(uint4*)&b1f.u[0] = *(const uint4*)(xbB_ + (size_t)tB * IN_F + q * 8);
        }
        // (3) claim tile+1 via shuffled meta (no ei re-read)
        if (hn) {
            int nodeS = __shfl(sB, clm_el), nodeT = __shfl(tB, clm_el);
            int eS = (tile + 1) * 16 + clm_el;
            if (lane < 8 && eS < E) {
                int node = clm_side ? nodeS : nodeT;
                int s = atomicAdd(&cursor[node], 1);
                __builtin_nontemporal_store(eS | (int)(((uint)clm_side) << 31), &list[s]);
            }
        }

        // ---- compute tile t ----
        f32x4 acc0, acc1;
#pragma unroll
        for (int r = 0; r < 4; r++) {
            acc0[r] = b1q[0][r] + eA_ * w1Lq[0][r];
            acc1[r] = b1q[1][r] + eA_ * w1Lq[1][r];
        }
        acc0 = __builtin_amdgcn_mfma_f32_16x16x32_bf16(w1f[0][0].v, a0.v, acc0, 0, 0, 0);
        acc0 = __builtin_amdgcn_mfma_f32_16x16x32_bf16(w1f[0][1].v, a1.v, acc0, 0, 0, 0);
        acc1 = __builtin_amdgcn_mfma_f32_16x16x32_bf16(w1f[1][0].v, a0.v, acc1, 0, 0, 0);
        acc1 = __builtin_amdgcn_mfma_f32_16x16x32_bf16(w1f[1][1].v, a1.v, acc1, 0, 0, 0);

        uint u0 = pk2f(sigmoidf_(acc0[0]), sigmoidf_(acc0[1]));
        uint u1 = pk2f(sigmoidf_(acc0[2]), sigmoidf_(acc0[3]));
        uint u2 = pk2f(sigmoidf_(acc1[0]), sigmoidf_(acc1[1]));
        uint u3 = pk2f(sigmoidf_(acc1[2]), sigmoidf_(acc1[3]));
        uint2 p01 = {u0, u1}, p23 = {u2, u3};
        *(uint2*)&hbuf[w][n16 * 40 + q * 4]      = p01;
        *(uint2*)&hbuf[w][n16 * 40 + 16 + q * 4] = p23;

        Frag ha;
        *(uint4*)&ha.u[0] = *(const uint4*)&hbuf[w][n16 * 40 + q * 8];

        f32x4 c0, c1;
#pragma unroll
        for (int r = 0; r < 4; r++) { c0[r] = b2q[0][r]; c1[r] = b2q[1][r]; }
        c0 = __builtin_amdgcn_mfma_f32_16x16x32_bf16(w2f[0].v, ha.v, c0, 0, 0, 0);
        c1 = __builtin_amdgcn_mfma_f32_16x16x32_bf16(w2f[1].v, ha.v, c1, 0, 0, 0);

        uint g0 = pk2f(sigmoidf_(c0[0]), sigmoidf_(c0[1]));
        uint g1 = pk2f(sigmoidf_(c0[2]), sigmoidf_(c0[3]));
        uint g2 = pk2f(sigmoidf_(c1[0]), sigmoidf_(c1[1]));
        uint g3 = pk2f(sigmoidf_(c1[2]), sigmoidf_(c1[3]));  // q==3: cols 30,31 = pad

        if (vA) {
            // batch-major plane: 16 uints (64 B) per edge, fully CONTIGUOUS
            // across the tile's 16 edges (1 KB streaming burst per wave)
            uint* bt = hplane + (size_t)(tile * 16 + n16) * 16;
            uint2 t01; t01.x = g0; t01.y = g1;
            uint2 t23; t23.x = g2; t23.y = g3;
            *(uint2*)(bt + q * 2)     = t01;
            *(uint2*)(bt + 8 + q * 2) = t23;
        }

        // shift pipeline
        sA = sB; tA = tB; eA_ = eB_; vA = vB;
        sB = sC; tB = tC; eB_ = eC_; vB = vC;
        a0 = b0; a1 = b1f;
    }
}

// ---------------------------------------------------------------------------
// List-indirect gather over batch-major h planes (h[b][e][32] bf16, 64 B per
// (b,e) row), ALL 4 batches in one pass, fused W3. One wave per node; lanes
// 0..59: bq=lane/15 (batch plane), jp=lane%15 (col-pair). 8-deep unrolled.
// ---------------------------------------------------------------------------
__global__ void __launch_bounds__(256) gather_e4(
    const ushort* __restrict__ h, const int* __restrict__ list,
    const int* __restrict__ offs, const float* __restrict__ W3,
    const float* __restrict__ b3, float* __restrict__ out, int E, int N) {
    __shared__ float sW3[H2_F * 32];
    __shared__ float sb3[32];
    __shared__ float sacc[4][B_SZ][H2_F];
    for (int i = threadIdx.x; i < H2_F * 32; i += 256) sW3[i] = W3[i];
    if (threadIdx.x < 32) sb3[threadIdx.x] = b3[threadIdx.x];
    __syncthreads();

    int w = threadIdx.x >> 6, lane = threadIdx.x & 63;
    int n = blockIdx.x * 4 + w;
    if (n >= N) return;

    int s = offs[n], e = offs[n + 1];
    int r = (lane < 60) ? lane : 0;
    int bq = r / 15, jp = r % 15;
    // per-lane plane base: h32 + bq*E*16 + jp
    const uint* hp = (const uint*)h + (size_t)bq * E * 16 + jp;
    float a0 = 0.f, a1 = 0.f;
    int i = (lane < 60) ? s : e;
    for (; i + 7 < e; i += 8) {
        int v0 = list[i],     v1 = list[i + 1], v2 = list[i + 2], v3 = list[i + 3];
        int v4 = list[i + 4], v5 = list[i + 5], v6 = list[i + 6], v7 = list[i + 7];
        uint d0 = hp[(size_t)(v0 & 0x7FFFFFFF) * 16];
        uint d1 = hp[(size_t)(v1 & 0x7FFFFFFF) * 16];
        uint d2 = hp[(size_t)(v2 & 0x7FFFFFFF) * 16];
        uint d3 = hp[(size_t)(v3 & 0x7FFFFFFF) * 16];
        uint d4 = hp[(size_t)(v4 & 0x7FFFFFFF) * 16];
        uint d5 = hp[(size_t)(v5 & 0x7FFFFFFF) * 16];
        uint d6 = hp[(size_t)(v6 & 0x7FFFFFFF) * 16];
        uint d7 = hp[(size_t)(v7 & 0x7FFFFFFF) * 16];
        float g0 = (v0 < 0) ? -1.f : 1.f, g1 = (v1 < 0) ? -1.f : 1.f;
        float g2 = (v2 < 0) ? -1.f : 1.f, g3 = (v3 < 0) ? -1.f : 1.f;
        float g4 = (v4 < 0) ? -1.f : 1.f, g5 = (v5 < 0) ? -1.f : 1.f;
        float g6 = (v6 < 0) ? -1.f : 1.f, g7 = (v7 < 0) ? -1.f : 1.f;
        a0 += g0 * bf2f((ushort)d0) + g1 * bf2f((ushort)d1)
            + g2 * bf2f((ushort)d2) + g3 * bf2f((ushort)d3)
            + g4 * bf2f((ushort)d4) + g5 * bf2f((ushort)d5)
            + g6 * bf2f((ushort)d6) + g7 * bf2f((ushort)d7);
        a1 += g0 * bf2f((ushort)(d0 >> 16)) + g1 * bf2f((ushort)(d1 >> 16))
            + g2 * bf2f((ushort)(d2 >> 16)) + g3 * bf2f((ushort)(d3 >> 16))
            + g4 * bf2f((ushort)(d4 >> 16)) + g5 * bf2f((ushort)(d5 >> 16))
            + g6 * bf2f((ushort)(d6 >> 16)) + g7 * bf2f((ushort)(d7 >> 16));
    }
    for (; i + 3 < e; i += 4) {
        int v0 = list[i], v1 = list[i + 1], v2 = list[i + 2], v3 = list[i + 3];
        uint d0 = hp[(size_t)(v0 & 0x7FFFFFFF) * 16];
        uint d1 = hp[(size_t)(v1 & 0x7FFFFFFF) * 16];
        uint d2 = hp[(size_t)(v2 & 0x7FFFFFFF) * 16];
        uint d3 = hp[(size_t)(v3 & 0x7FFFFFFF) * 16];
        float g0 = (v0 < 0) ? -1.f : 1.f;
        float g1 = (v1 < 0) ? -1.f : 1.f;
        float g2 = (v2 < 0) ? -1.f : 1.f;
        float g3 = (v3 < 0) ? -1.f : 1.f;
        a0 += g0 * bf2f((ushort)d0) + g1 * bf2f((ushort)d1)
            + g2 * bf2f((ushort)d2) + g3 * bf2f((ushort)d3);
        a1 += g0 * bf2f((ushort)(d0 >> 16)) + g1 * bf2f((ushort)(d1 >> 16))
            + g2 * bf2f((ushort)(d2 >> 16)) + g3 * bf2f((ushort)(d3 >> 16));
    }
    for (; i < e; i++) {
        int v = list[i];
        uint d = hp[(size_t)(v & 0x7FFFFFFF) * 16];
        float g = (v < 0) ? -1.f : 1.f;
        a0 += g * bf2f((ushort)d);
        a1 += g * bf2f((ushort)(d >> 16));
    }
    if (lane < 60) {
        sacc[w][bq][jp * 2]     = a0;
        sacc[w][bq][jp * 2 + 1] = a1;
    }
    int b = lane >> 4, k = lane & 15;
    float o0 = sb3[k], o1 = sb3[k + 16];
#pragma unroll
    for (int j = 0; j < H2_F; j++) {
        float v = sacc[w][b][j];
        o0 += v * sW3[j * 32 + k];
        o1 += v * sW3[j * 32 + k + 16];
    }
    float* op = out + ((size_t)b * N + n) * 32;
    op[k]      = sigmoidf_(o0);
    op[k + 16] = sigmoidf_(o1);
}

// ---------------------------------------------------------------------------
// FALLBACK tier (round-5 path): scatter list + list-indirect gather
// ---------------------------------------------------------------------------
__global__ void __launch_bounds__(256) scatter_kernel(const int* __restrict__ ei,
                                                      int* __restrict__ cursor,
                                                      int* __restrict__ list, int E, int N) {
    int e = blockIdx.x * 256 + threadIdx.x;
    if (e < E) {
        int tgt = ei[E + e];
        int p = atomicAdd(&cursor[tgt], 1);
        list[p] = e;
        int src = ei[e];
        int q = atomicAdd(&cursor[src], 1);
        list[q] = e | (int)0x80000000u;
    }
}

template<bool USE_XB>
__global__ void __launch_bounds__(256) edge_mlp_mfma2(
    const float* __restrict__ x, const ushort* __restrict__ xb,
    const int* __restrict__ ei, const float* __restrict__ ea,
    const float* __restrict__ W1, const float* __restrict__ b1,
    const float* __restrict__ W2, const float* __restrict__ b2,
    const float* __restrict__ sums, ushort* __restrict__ h,
    int E, int N, int tiles) {
    __shared__ ushort __attribute__((aligned(16))) hbuf[4][16 * 40];
    int w = threadIdx.x >> 6;
    int lane = threadIdx.x & 63;
    int n16 = lane & 15;
    int q = lane >> 4;

    Frag w1f[2][2];
#pragma unroll
    for (int t = 0; t < 2; t++)
#pragma unroll
        for (int s = 0; s < 2; s++)
#pragma unroll
            for (int j = 0; j < 4; j++) {
                int k0 = 32 * s + q * 8 + 2 * j;
                w1f[t][s].u[j] = pk2(W1[(size_t)k0 * 32 + 16 * t + n16],
                                     W1[(size_t)(k0 + 1) * 32 + 16 * t + n16]);
            }
    Frag w2f[2];
#pragma unroll
    for (int t = 0; t < 2; t++) {
        int m = 16 * t + n16;
#pragma unroll
        for (int j = 0; j < 4; j++) {
            int k0 = q * 8 + 2 * j;
            float a = (m < H2_F) ? W2[(size_t)k0 * H2_F + m] : 0.f;
            float d = (m < H2_F) ? W2[(size_t)(k0 + 1) * H2_F + m] : 0.f;
            w2f[t].u[j] = pk2(a, d);
        }
    }
    float b1q[2][4], w1Lq[2][4], b2q[2][4];
#pragma unroll
    for (int t = 0; t < 2; t++)
#pragma unroll
        for (int r = 0; r < 4; r++) {
            int col = 16 * t + q * 4 + r;
            b1q[t][r]  = b1[col];
            w1Lq[t][r] = W1[(size_t)64 * 32 + col];
            b2q[t][r]  = (col < H2_F) ? b2[col] : 0.f;
        }

    float mean = sums[0] / (float)E;
    float var = (sums[1] - (float)E * mean * mean) / (float)(E - 1);
    float istd = rsqrtf(var);

    int b = n16 & 3;
    int eoff = n16 >> 2;
    int gw = blockIdx.x * 4 + w;

    for (int tix = 0; tix < TPW; ++tix) {
        int tile = gw * TPW + tix;
        if (tile >= tiles) break;
        int e0 = tile * 4;
        int eA = e0 + eoff;
        bool vrow = eA < E;
        int eAc = vrow ? eA : E - 1;
        int src = ei[eAc], tgt = ei[E + eAc];
        float eav = (ea[eAc] - mean) * istd;

        Frag a0, a1;
        if (USE_XB) {
            *(uint4*)&a0.u[0] = *(const uint4*)(xb + ((size_t)b * N + src) * IN_F + q * 8);
            *(uint4*)&a1.u[0] = *(const uint4*)(xb + ((size_t)b * N + tgt) * IN_F + q * 8);
        } else {
            const float4* ps = (const float4*)(x + ((size_t)b * N + src) * IN_F + q * 8);
            float4 s0 = ps[0], s1 = ps[1];
            const float4* pt = (const float4*)(x + ((size_t)b * N + tgt) * IN_F + q * 8);
            float4 t0 = pt[0], t1 = pt[1];
            a0.u[0] = pk2(s0.x, s0.y); a0.u[1] = pk2(s0.z, s0.w);
            a0.u[2] = pk2(s1.x, s1.y); a0.u[3] = pk2(s1.z, s1.w);
            a1.u[0] = pk2(t0.x, t0.y); a1.u[1] = pk2(t0.z, t0.w);
            a1.u[2] = pk2(t1.x, t1.y); a1.u[3] = pk2(t1.z, t1.w);
        }

        f32x4 acc0, acc1;
#pragma unroll
        for (int r = 0; r < 4; r++) {
            acc0[r] = b1q[0][r] + eav * w1Lq[0][r];
            acc1[r] = b1q[1][r] + eav * w1Lq[1][r];
        }
        acc0 = __builtin_amdgcn_mfma_f32_16x16x32_bf16(w1f[0][0].v, a0.v, acc0, 0, 0, 0);
        acc0 = __builtin_amdgcn_mfma_f32_16x16x32_bf16(w1f[0][1].v, a1.v, acc0, 0, 0, 0);
        acc1 = __builtin_amdgcn_mfma_f32_16x16x32_bf16(w1f[1][0].v, a0.v, acc1, 0, 0, 0);
        acc1 = __builtin_amdgcn_mfma_f32_16x16x32_bf16(w1f[1][1].v, a1.v, acc1, 0, 0, 0);

        uint u0 = pk2(sigmoidf_(acc0[0]), sigmoidf_(acc0[1]));
        uint u1 = pk2(sigmoidf_(acc0[2]), sigmoidf_(acc0[3]));
        uint u2 = pk2(sigmoidf_(acc1[0]), sigmoidf_(acc1[1]));
        uint u3 = pk2(sigmoidf_(acc1[2]), sigmoidf_(acc1[3]));
        uint2 p01 = {u0, u1}, p23 = {u2, u3};
        *(uint2*)&hbuf[w][n16 * 40 + q * 4]      = p01;
        *(uint2*)&hbuf[w][n16 * 40 + 16 + q * 4] = p23;

        Frag ha;
        *(uint4*)&ha.u[0] = *(const uint4*)&hbuf[w][n16 * 40 + q * 8];

        f32x4 c0, c1;
#pragma unroll
        for (int r = 0; r < 4; r++) { c0[r] = b2q[0][r]; c1[r] = b2q[1][r]; }
        c0 = __builtin_amdgcn_mfma_f32_16x16x32_bf16(w2f[0].v, ha.v, c0, 0, 0, 0);
        c1 = __builtin_amdgcn_mfma_f32_16x16x32_bf16(w2f[1].v, ha.v, c1, 0, 0, 0);

        uint g0 = pk2(sigmoidf_(c0[0]), sigmoidf_(c0[1]));
        uint g1 = pk2(sigmoidf_(c0[2]), sigmoidf_(c0[3]));
        uint g2 = pk2(sigmoidf_(c1[0]), sigmoidf_(c1[1]));
        uint g3 = pk2(sigmoidf_(c1[2]), sigmoidf_(c1[3]));
        if (vrow) {
            uint* base = (uint*)(h + (size_t)(e0 * 4 + n16) * H2_F);
            base[q * 2]     = g0;
            base[q * 2 + 1] = g1;
            base[8 + q * 2] = g2;
            if (q < 3) base[8 + q * 2 + 1] = g3;
        }
    }
}

__global__ void __launch_bounds__(256) gather_final(
    const ushort* __restrict__ h, const int* __restrict__ list,
    const int* __restrict__ offs, const float* __restrict__ W3,
    const float* __restrict__ b3, float* __restrict__ out, int N) {
    __shared__ float sW3[H2_F * 32];
    __shared__ float sb3[32];
    __shared__ float sacc[4][B_SZ][H2_F];
    for (int i = threadIdx.x; i < H2_F * 32; i += 256) sW3[i] = W3[i];
    if (threadIdx.x < 32) sb3[threadIdx.x] = b3[threadIdx.x];
    __syncthreads();

    int w = threadIdx.x >> 6, lane = threadIdx.x & 63;
    int n = blockIdx.x * 4 + w;
    if (n >= N) return;

    if (lane < 60) {
        int bq = lane / 15, jp = lane % 15;
        float a0 = 0.f, a1 = 0.f;
        int s = offs[n], e = offs[n + 1];
        int i = s;
        for (; i + 4 <= e; i += 4) {
            int v0 = list[i], v1 = list[i + 1], v2 = list[i + 2], v3 = list[i + 3];
            uint d0 = *(const uint*)(h + (size_t)(v0 & 0x7FFFFFFF) * 120 + bq * 30 + jp * 2);
            uint d1 = *(const uint*)(h + (size_t)(v1 & 0x7FFFFFFF) * 120 + bq * 30 + jp * 2);
            uint d2 = *(const uint*)(h + (size_t)(v2 & 0x7FFFFFFF) * 120 + bq * 30 + jp * 2);
            uint d3 = *(const uint*)(h + (size_t)(v3 & 0x7FFFFFFF) * 120 + bq * 30 + jp * 2);
            float g0 = (v0 < 0) ? -1.f : 1.f;
            float g1 = (v1 < 0) ? -1.f : 1.f;
            float g2 = (v2 < 0) ? -1.f : 1.f;
            float g3 = (v3 < 0) ? -1.f : 1.f;
            a0 += g0 * bf2f((ushort)d0) + g1 * bf2f((ushort)d1)
                + g2 * bf2f((ushort)d2) + g3 * bf2f((ushort)d3);
            a1 += g0 * bf2f((ushort)(d0 >> 16)) + g1 * bf2f((ushort)(d1 >> 16))
                + g2 * bf2f((ushort)(d2 >> 16)) + g3 * bf2f((ushort)(d3 >> 16));
        }
        for (; i < e; i++) {
            int v = list[i];
            uint d = *(const uint*)(h + (size_t)(v & 0x7FFFFFFF) * 120 + bq * 30 + jp * 2);
            float g = (v < 0) ? -1.f : 1.f;
            a0 += g * bf2f((ushort)d);
            a1 += g * bf2f((ushort)(d >> 16));
        }
        sacc[w][bq][jp * 2]     = a0;
        sacc[w][bq][jp * 2 + 1] = a1;
    }
    int b = lane >> 4, k = lane & 15;
    float o0 = sb3[k], o1 = sb3[k + 16];
#pragma unroll
    for (int j = 0; j < H2_F; j++) {
        float v = sacc[w][b][j];
        o0 += v * sW3[j * 32 + k];
        o1 += v * sW3[j * 32 + k + 16];
    }
    float* op = out + ((size_t)b * N + n) * 32;
    op[k]      = sigmoidf_(o0);
    op[k + 16] = sigmoidf_(o1);
}

// ---------------------------------------------------------------------------
extern "C" void kernel_launch(void* const* d_in, const int* in_sizes, int n_in,
                              void* d_out, int out_size, void* d_ws, size_t ws_size,
                              hipStream_t stream) {
    const float* x  = (const float*)d_in[0];
    const int*   ei = (const int*)d_in[1];
    const float* ea = (const float*)d_in[2];
    const float* W1 = (const float*)d_in[3];
    const float* b1 = (const float*)d_in[4];
    const float* W2 = (const float*)d_in[5];
    const float* b2 = (const float*)d_in[6];
    const float* W3 = (const float*)d_in[7];
    const float* b3 = (const float*)d_in[8];
    float* out = (float*)d_out;

    const int E  = in_sizes[2];
    const int N  = in_sizes[0] / (B_SZ * IN_F);
    const int BN = B_SZ * N;
    const int nb = (N + 1023) / 1024;
    const long long n8 = (long long)BN * IN_F / 8;
    const int nblkC = (int)(((long long)E > n8 ? (long long)E : n8) + 255) / 256;

    char* base = (char*)d_ws;

    // ---- tier A: batch-major h planes (4 x E x 64 B) + sign list ----
    size_t off = 0;
    int* cnt    = (int*)(base + off); off += (size_t)HREP * N * 4;  // replicated histogram
    float* sums = (float*)(base + off); off += 8;
    int* offs   = (int*)(base + off); off += (size_t)(N + 1) * 4;
    int* cursor = (int*)(base + off); off += (size_t)N * 4;
    int* bsum   = (int*)(base + off); off += 4096;
    off = (off + 255) & ~(size_t)255;
    float2* psums = (float2*)(base + off); off += (size_t)nblkC * 8;
    off = (off + 255) & ~(size_t)255;
    int* list   = (int*)(base + off); off += (size_t)2 * E * 4;
    off = (off + 255) & ~(size_t)255;
    ushort* h   = (ushort*)(base + off); off += (size_t)E * 256;   // 4 planes x E x 64 B
    off = (off + 255) & ~(size_t)255;
    ushort* xb  = (ushort*)(base + off); off += (size_t)BN * IN_F * 2;
    size_t needA = off;

    // ---- tier B (fallback): scatter list + e-indexed 120B h ----
    size_t offB = 0;
    int* cntB    = (int*)(base + offB); offB += (size_t)HREP * N * 4;
    float* sumsB = (float*)(base + offB); offB += 8;
    int* offsB   = (int*)(base + offB); offB += (size_t)(N + 1) * 4;
    int* cursorB = (int*)(base + offB); offB += (size_t)N * 4;
    int* bsumB   = (int*)(base + offB); offB += 4096;
    offB = (offB + 255) & ~(size_t)255;
    float2* psumsB = (float2*)(base + offB); offB += (size_t)nblkC * 8;
    int* listB   = (int*)(base + offB); offB += (size_t)2 * E * 4;
    offB = (offB + 255) & ~(size_t)255;
    ushort* hB   = (ushort*)(base + offB); offB += (size_t)E * 240;
    offB = (offB + 255) & ~(size_t)255;
    ushort* xbB  = (ushort*)(base + offB);
    size_t needB = offB + (size_t)BN * IN_F * 2;

    if (ws_size >= needA) {
        const int tiles = (E + 15) / 16;                 // 16 edges per tile, 1 batch
        const int wpb = (tiles + TPW - 1) / TPW;         // waves per batch
        const int bpb = (wpb + 3) / 4;                   // blocks per batch
        hipMemsetAsync(cnt, 0, (size_t)HREP * N * 4 + 8, stream);  // cnt replicas + sums
        stats_xcvt_kernel<<<nblkC, 256, 0, stream>>>(ea, ei, x, psums, cnt, xb, E, N, n8);
        sums_reduce_kernel<<<1, 256, 0, stream>>>(psums, sums, nblkC);
        scan1_kernel<<<nb, 256, 0, stream>>>(cnt, offs, bsum, N);
        scan2_kernel<<<1, 64, 0, stream>>>(bsum, offs, nb, N);
        scan3_kernel<<<nb, 256, 0, stream>>>(offs, cursor, bsum, N);
        // batch-major single pass: 4*bpb blocks, batch = blockIdx / bpb
        edge_mlp_e4<<<B_SZ * bpb, 256, 0, stream>>>(xb, ei, ea, W1, b1, W2, b2,
                                                    sums, cursor, list, h, E, N, tiles, bpb);
        gather_e4<<<(N + 3) / 4, 256, 0, stream>>>(h, list, offs, W3, b3, out, E, N);
    } else {
        const int tiles = (E + 3) / 4;
        const int waves = (tiles + TPW - 1) / TPW;
        const int eblocks = (waves + 3) / 4;
        bool use_xb = (ws_size >= needB);
        hipMemsetAsync(cntB, 0, (size_t)HREP * N * 4 + 8, stream);
        stats_xcvt_kernel<<<nblkC, 256, 0, stream>>>(ea, ei, x, psumsB, cntB,
                                                     use_xb ? xbB : (ushort*)nullptr,
                                                     E, N, use_xb ? n8 : 0LL);
        sums_reduce_kernel<<<1, 256, 0, stream>>>(psumsB, sumsB, nblkC);
        scan1_kernel<<<nb, 256, 0, stream>>>(cntB, offsB, bsumB, N);
        scan2_kernel<<<1, 64, 0, stream>>>(bsumB, offsB, nb, N);
        scan3_kernel<<<nb, 256, 0, stream>>>(offsB, cursorB, bsumB, N);
        scatter_kernel<<<(E + 255) / 256, 256, 0, stream>>>(ei, cursorB, listB, E, N);
        if (use_xb)
            edge_mlp_mfma2<true><<<eblocks, 256, 0, stream>>>(x, xbB, ei, ea, W1, b1,
                                                              W2, b2, sumsB, hB, E, N, tiles);
        else
            edge_mlp_mfma2<false><<<eblocks, 256, 0, stream>>>(x, xbB, ei, ea, W1, b1,
                                                               W2, b2, sumsB, hB, E, N, tiles);
        gather_final<<<(N + 3) / 4, 256, 0, stream>>>(hB, listB, offsB, W3, b3, out, N);
    }
}

// Round 13
// 406.095 us; speedup vs baseline: 1.0883x; 1.0883x over previous
//
#include <hip/hip_runtime.h>
#include <math.h>

#define B_SZ 4
#define IN_F 32
#define H1_F 32
#define H2_F 30
#define TPW 16   // tiles per wave in edge kernel
#define HREP 16  // histogram replicas (atomic hot-line chain reduction)

typedef unsigned int uint;
typedef unsigned short ushort;
typedef unsigned long long ull;
typedef __attribute__((ext_vector_type(8))) short bf16x8;
typedef __attribute__((ext_vector_type(4))) float f32x4;

__device__ __forceinline__ float fastrcp(float x) {
#if __has_builtin(__builtin_amdgcn_rcpf)
    return __builtin_amdgcn_rcpf(x);
#else
    return 1.f / x;
#endif
}
__device__ __forceinline__ float sigmoidf_(float x) {
    return fastrcp(1.f + __expf(-x));
}

__device__ __forceinline__ ushort f2bf(float f) {
    uint u = __float_as_uint(f);
    return (ushort)((u + 0x7FFFu + ((u >> 16) & 1u)) >> 16);  // RNE
}
__device__ __forceinline__ float bf2f(ushort v) { return __uint_as_float(((uint)v) << 16); }
__device__ __forceinline__ uint pk2(float a, float b) {
    return (uint)f2bf(a) | ((uint)f2bf(b) << 16);
}
// HW packed f32->bf16 (RNE), 1 instruction per pair.
__device__ __forceinline__ uint pk2f(float a, float b) {
    uint r;
    asm("v_cvt_pk_bf16_f32 %0, %1, %2" : "=v"(r) : "v"(a), "v"(b));
    return r;
}

union Frag { bf16x8 v; ushort us[8]; uint u[4]; };

// ---------------------------------------------------------------------------
// MERGED: ea stats (per-block partials) + degree histogram (HREP-replicated,
// fire-and-forget atomics) + x f32->bf16 conversion.
// ---------------------------------------------------------------------------
__global__ void __launch_bounds__(256) stats_xcvt_kernel(
    const float* __restrict__ ea, const int* __restrict__ ei,
    const float* __restrict__ x, float2* __restrict__ psums,
    int* __restrict__ cnt, ushort* __restrict__ xb,
    int E, int N, long long n8) {
    long long i = (long long)blockIdx.x * 256 + threadIdx.x;
    if (i < n8) {
        const float4* p = (const float4*)(x + i * 8);
        float4 v0 = p[0], v1 = p[1];
        uint4 o;
        o.x = pk2f(v0.x, v0.y); o.y = pk2f(v0.z, v0.w);
        o.z = pk2f(v1.x, v1.y); o.w = pk2f(v1.z, v1.w);
        *(uint4*)(xb + i * 8) = o;
    }
    int e = blockIdx.x * 256 + threadIdx.x;
    int* myc = cnt + (size_t)(blockIdx.x & (HREP - 1)) * N;
    float a = (e < E) ? ea[e] : 0.f;
    if (e < E) {
        atomicAdd(&myc[ei[E + e]], 1);
        atomicAdd(&myc[ei[e]], 1);
    }
    float v = a, v2 = a * a;
    for (int off = 32; off > 0; off >>= 1) {
        v  += __shfl_down(v, off);
        v2 += __shfl_down(v2, off);
    }
    __shared__ float s1[4], s2[4];
    int wid = threadIdx.x >> 6, lane = threadIdx.x & 63;
    if (lane == 0) { s1[wid] = v; s2[wid] = v2; }
    __syncthreads();
    if (threadIdx.x == 0) {
        float2 p;
        p.x = s1[0] + s1[1] + s1[2] + s1[3];
        p.y = s2[0] + s2[1] + s2[2] + s2[3];
        psums[blockIdx.x] = p;
    }
}

// single-block reduction of per-block partials -> sums[0..1]
__global__ void __launch_bounds__(256) sums_reduce_kernel(
    const float2* __restrict__ psums, float* __restrict__ sums, int nblk) {
    float v = 0.f, v2 = 0.f;
    for (int i = threadIdx.x; i < nblk; i += 256) {
        float2 p = psums[i];
        v += p.x; v2 += p.y;
    }
    for (int off = 32; off > 0; off >>= 1) {
        v  += __shfl_down(v, off);
        v2 += __shfl_down(v2, off);
    }
    __shared__ float s1[4], s2[4];
    int wid = threadIdx.x >> 6, lane = threadIdx.x & 63;
    if (lane == 0) { s1[wid] = v; s2[wid] = v2; }
    __syncthreads();
    if (threadIdx.x == 0) {
        sums[0] = s1[0] + s1[1] + s1[2] + s1[3];
        sums[1] = s2[0] + s2[1] + s2[2] + s2[3];
    }
}

// ---------------------------------------------------------------------------
// 3-phase multi-block exclusive scan; phase 1 sums the HREP replicas.
// ---------------------------------------------------------------------------
__global__ void __launch_bounds__(256) scan1_kernel(const int* __restrict__ cnt,
                                                    int* __restrict__ offs,
                                                    int* __restrict__ bsum, int n) {
    __shared__ int wtot[4];
    int base = blockIdx.x * 1024 + threadIdx.x * 4;
    int4 v = {0, 0, 0, 0};
    if (base + 3 < n) {
#pragma unroll
        for (int r = 0; r < HREP; r++) {
            int4 t = *(const int4*)(cnt + (size_t)r * n + base);
            v.x += t.x; v.y += t.y; v.z += t.z; v.w += t.w;
        }
    } else {
        for (int r = 0; r < HREP; r++) {
            const int* c = cnt + (size_t)r * n;
            if (base < n)     v.x += c[base];
            if (base + 1 < n) v.y += c[base + 1];
            if (base + 2 < n) v.z += c[base + 2];
            if (base + 3 < n) v.w += c[base + 3];
        }
    }
    int s = v.x + v.y + v.z + v.w;
    int incl = s;
    int lane = threadIdx.x & 63;
    for (int d = 1; d < 64; d <<= 1) {
        int t = __shfl_up(incl, d);
        if (lane >= d) incl += t;
    }
    int wid = threadIdx.x >> 6;
    if (lane == 63) wtot[wid] = incl;
    __syncthreads();
    int woff = 0, tot = 0;
#pragma unroll
    for (int w = 0; w < 4; w++) {
        int t = wtot[w];
        if (w < wid) woff += t;
        tot += t;
    }
    int excl = woff + incl - s;
    int4 o;
    o.x = excl; o.y = excl + v.x; o.z = o.y + v.y; o.w = o.z + v.z;
    if (base + 3 < n) *(int4*)(offs + base) = o;
    else {
        if (base < n)     offs[base] = o.x;
        if (base + 1 < n) offs[base + 1] = o.y;
        if (base + 2 < n) offs[base + 2] = o.z;
        if (base + 3 < n) offs[base + 3] = o.w;
    }
    if (threadIdx.x == 0) bsum[blockIdx.x] = tot;
}

__global__ void scan2_kernel(int* __restrict__ bsum, int* __restrict__ offs,
                             int nb, int n) {
    int lane = threadIdx.x;
    if (nb <= 64) {
        int v = (lane < nb) ? bsum[lane] : 0;
        int incl = v;
        for (int d = 1; d < 64; d <<= 1) {
            int t = __shfl_up(incl, d);
            if (lane >= d) incl += t;
        }
        if (lane < nb) bsum[lane] = incl - v;
        if (lane == 63) offs[n] = incl;
    } else if (lane == 0) {
        int run = 0;
        for (int i = 0; i < nb; i++) { int t = bsum[i]; bsum[i] = run; run += t; }
        offs[n] = run;
    }
}

__global__ void __launch_bounds__(256) scan3_kernel(int* __restrict__ offs,
                                                    int* __restrict__ cursor,
                                                    const int* __restrict__ bsum, int n) {
    int base = blockIdx.x * 1024 + threadIdx.x * 4;
    int add = bsum[blockIdx.x];
    if (base + 3 < n) {
        int4 v = *(const int4*)(offs + base);
        v.x += add; v.y += add; v.z += add; v.w += add;
        *(int4*)(offs + base) = v;
        *(int4*)(cursor + base) = v;
    } else {
        for (int k = 0; k < 4; k++) {
            int i = base + k;
            if (i < n) { int v = offs[i] + add; offs[i] = v; cursor[i] = v; }
        }
    }
}

// ---------------------------------------------------------------------------
// BATCH-MAJOR edge MLP, SPLIT-DEPTH PIPELINE (r11: meta 2 ahead, xb 1 ahead,
// claims via __shfl). h layout REVERTED to e-indexed [e][4][32] (256 B slots)
// -- r12's batch-major planes sped the producer (-9us) but cost the gather
// ~+40us by splitting one slot's 4 batch lines across 4 distant planes.
// Consumer locality wins. Batch-major grid (r10): blocks [b*bpb,(b+1)*bpb)
// share one 3.2 MB xb slice per XCD L2. Claims: prologue claims tile0, iter
// tix claims tile0+tix+1 -> each (edge,side) exactly once.
// ---------------------------------------------------------------------------
__global__ void __launch_bounds__(256) edge_mlp_e4(
    const ushort* __restrict__ xb,
    const int* __restrict__ ei, const float* __restrict__ ea,
    const float* __restrict__ W1, const float* __restrict__ b1,
    const float* __restrict__ W2, const float* __restrict__ b2,
    const float* __restrict__ sums, int* __restrict__ cursor,
    int* __restrict__ list, ushort* __restrict__ h,
    int E, int N, int tiles, int bpb) {
    __shared__ ushort __attribute__((aligned(16))) hbuf[4][16 * 40];
    int w = threadIdx.x >> 6;
    int lane = threadIdx.x & 63;
    int n16 = lane & 15;             // edge-local index within tile
    int q = lane >> 4;

    int b   = blockIdx.x / bpb;      // batch (batch-major grid)
    int blk = blockIdx.x % bpb;

    // weight fragments as operand A (= W^T)
    Frag w1f[2][2];
#pragma unroll
    for (int t = 0; t < 2; t++)
#pragma unroll
        for (int s = 0; s < 2; s++)
#pragma unroll
            for (int j = 0; j < 4; j++) {
                int k0 = 32 * s + q * 8 + 2 * j;
                w1f[t][s].u[j] = pk2(W1[(size_t)k0 * 32 + 16 * t + n16],
                                     W1[(size_t)(k0 + 1) * 32 + 16 * t + n16]);
            }
    Frag w2f[2];
#pragma unroll
    for (int t = 0; t < 2; t++) {
        int m = 16 * t + n16;
#pragma unroll
        for (int j = 0; j < 4; j++) {
            int k0 = q * 8 + 2 * j;
            float a = (m < H2_F) ? W2[(size_t)k0 * H2_F + m] : 0.f;
            float d = (m < H2_F) ? W2[(size_t)(k0 + 1) * H2_F + m] : 0.f;
            w2f[t].u[j] = pk2(a, d);
        }
    }
    float b1q[2][4], w1Lq[2][4], b2q[2][4];
#pragma unroll
    for (int t = 0; t < 2; t++)
#pragma unroll
        for (int r = 0; r < 4; r++) {
            int col = 16 * t + q * 4 + r;
            b1q[t][r]  = b1[col];
            w1Lq[t][r] = W1[(size_t)64 * 32 + col];
            b2q[t][r]  = (col < H2_F) ? b2[col] : 0.f;
        }

    float mean = sums[0] / (float)E;
    float var = (sums[1] - (float)E * mean * mean) / (float)(E - 1);
    float istd = rsqrtf(var);

    int gw = blk * 4 + w;
    int tile0 = gw * TPW;
    if (tile0 >= tiles) return;
    const ushort* xbB_ = xb + (size_t)b * N * IN_F;

    // slot-claim lane mapping: lanes 0..7 -> el = 4*(lane>>1)+b, side = lane&1
    int clm_el = 4 * (lane >> 1) + b;
    int clm_side = lane & 1;

    // ---- pipeline state: meta A = tile t, meta B = tile t+1; frags = tile t
    int sA, tA; float eA_; bool vA;
    int sB = 0, tB = 0; float eB_ = 0.f; bool vB = false;
    Frag a0, a1;

    {
        int e0 = tile0 * 16 + n16; vA = e0 < E; int c = vA ? e0 : E - 1;
        sA = ei[c]; tA = ei[E + c]; eA_ = (ea[c] - mean) * istd;
    }
    if (TPW > 1 && tile0 + 1 < tiles) {
        int e1 = (tile0 + 1) * 16 + n16; vB = e1 < E; int c = vB ? e1 : E - 1;
        sB = ei[c]; tB = ei[E + c]; eB_ = (ea[c] - mean) * istd;
    }
    *(uint4*)&a0.u[0] = *(const uint4*)(xbB_ + (size_t)sA * IN_F + q * 8);
    *(uint4*)&a1.u[0] = *(const uint4*)(xbB_ + (size_t)tA * IN_F + q * 8);
    {
        int nodeS = __shfl(sA, clm_el), nodeT = __shfl(tA, clm_el);
        int eS = tile0 * 16 + clm_el;
        if (lane < 8 && eS < E) {
            int node = clm_side ? nodeS : nodeT;
            int s = atomicAdd(&cursor[node], 1);
            __builtin_nontemporal_store(eS | (int)(((uint)clm_side) << 31), &list[s]);
        }
    }

    for (int tix = 0; tix < TPW; ++tix) {
        int tile = tile0 + tix;
        if (tile >= tiles) break;

        // (1) meta prefetch for tile+2 (independent loads)
        int sC = 0, tC = 0; float eC_ = 0.f; bool vC = false;
        if (tix + 2 < TPW && tile + 2 < tiles) {
            int e2 = (tile + 2) * 16 + n16; vC = e2 < E; int c = vC ? e2 : E - 1;
            sC = ei[c]; tC = ei[E + c]; eC_ = (ea[c] - mean) * istd;
        }
        // (2) xb prefetch for tile+1 (meta B resident for a full iteration)
        Frag b0, b1f;
        b0.u[0] = b0.u[1] = b0.u[2] = b0.u[3] = 0; b1f = b0;
        bool hn = (tix + 1 < TPW) && (tile + 1 < tiles);
        if (hn) {
            *(uint4*)&b0.u[0]  = *(const uint4*)(xbB_ + (size_t)sB * IN_F + q * 8);
            *(uint4*)&b1f.u[0] = *(const uint4*)(xbB_ + (size_t)tB * IN_F + q * 8);
        }
        // (3) claim tile+1 via shuffled meta (no ei re-read)
        if (hn) {
            int nodeS = __shfl(sB, clm_el), nodeT = __shfl(tB, clm_el);
            int eS = (tile + 1) * 16 + clm_el;
            if (lane < 8 && eS < E) {
                int node = clm_side ? nodeS : nodeT;
                int s = atomicAdd(&cursor[node], 1);
                __builtin_nontemporal_store(eS | (int)(((uint)clm_side) << 31), &list[s]);
            }
        }

        // ---- compute tile t ----
        f32x4 acc0, acc1;
#pragma unroll
        for (int r = 0; r < 4; r++) {
            acc0[r] = b1q[0][r] + eA_ * w1Lq[0][r];
            acc1[r] = b1q[1][r] + eA_ * w1Lq[1][r];
        }
        acc0 = __builtin_amdgcn_mfma_f32_16x16x32_bf16(w1f[0][0].v, a0.v, acc0, 0, 0, 0);
        acc0 = __builtin_amdgcn_mfma_f32_16x16x32_bf16(w1f[0][1].v, a1.v, acc0, 0, 0, 0);
        acc1 = __builtin_amdgcn_mfma_f32_16x16x32_bf16(w1f[1][0].v, a0.v, acc1, 0, 0, 0);
        acc1 = __builtin_amdgcn_mfma_f32_16x16x32_bf16(w1f[1][1].v, a1.v, acc1, 0, 0, 0);

        uint u0 = pk2f(sigmoidf_(acc0[0]), sigmoidf_(acc0[1]));
        uint u1 = pk2f(sigmoidf_(acc0[2]), sigmoidf_(acc0[3]));
        uint u2 = pk2f(sigmoidf_(acc1[0]), sigmoidf_(acc1[1]));
        uint u3 = pk2f(sigmoidf_(acc1[2]), sigmoidf_(acc1[3]));
        uint2 p01 = {u0, u1}, p23 = {u2, u3};
        *(uint2*)&hbuf[w][n16 * 40 + q * 4]      = p01;
        *(uint2*)&hbuf[w][n16 * 40 + 16 + q * 4] = p23;

        Frag ha;
        *(uint4*)&ha.u[0] = *(const uint4*)&hbuf[w][n16 * 40 + q * 8];

        f32x4 c0, c1;
#pragma unroll
        for (int r = 0; r < 4; r++) { c0[r] = b2q[0][r]; c1[r] = b2q[1][r]; }
        c0 = __builtin_amdgcn_mfma_f32_16x16x32_bf16(w2f[0].v, ha.v, c0, 0, 0, 0);
        c1 = __builtin_amdgcn_mfma_f32_16x16x32_bf16(w2f[1].v, ha.v, c1, 0, 0, 0);

        uint g0 = pk2f(sigmoidf_(c0[0]), sigmoidf_(c0[1]));
        uint g1 = pk2f(sigmoidf_(c0[2]), sigmoidf_(c0[3]));
        uint g2 = pk2f(sigmoidf_(c1[0]), sigmoidf_(c1[1]));
        uint g3 = pk2f(sigmoidf_(c1[2]), sigmoidf_(c1[3]));  // q==3: cols 30,31 = pad

        if (vA) {
            // e-indexed slot = 64 uints (256 B); this block's batch row = 16 uints (64 B line)
            uint* bt = (uint*)h + (size_t)(tile * 16 + n16) * 64 + b * 16;
            uint2 t01; t01.x = g0; t01.y = g1;
            uint2 t23; t23.x = g2; t23.y = g3;
            *(uint2*)(bt + q * 2)     = t01;
            *(uint2*)(bt + 8 + q * 2) = t23;
        }

        // shift pipeline
        sA = sB; tA = tB; eA_ = eB_; vA = vB;
        sB = sC; tB = tC; eB_ = eC_; vB = vC;
        a0 = b0; a1 = b1f;
    }
}

// ---------------------------------------------------------------------------
// List-indirect gather over 256B-aligned e-indexed h, ALL 4 batches in one
// pass, fused W3. One wave per node; lanes 0..59: bq=lane/15 (batch),
// jp=lane%15 (col-pair). NEW (r13): the list reads are software-pipelined
// one 8-group ahead (register double-buffer) so the dependent h loads of
// group k issue while group k+1's list entries are in flight -- removes the
// list-load latency from the per-group critical path.
// ---------------------------------------------------------------------------
__global__ void __launch_bounds__(256) gather_e4(
    const ushort* __restrict__ h, const int* __restrict__ list,
    const int* __restrict__ offs, const float* __restrict__ W3,
    const float* __restrict__ b3, float* __restrict__ out, int N) {
    __shared__ float sW3[H2_F * 32];
    __shared__ float sb3[32];
    __shared__ float sacc[4][B_SZ][H2_F];
    for (int i = threadIdx.x; i < H2_F * 32; i += 256) sW3[i] = W3[i];
    if (threadIdx.x < 32) sb3[threadIdx.x] = b3[threadIdx.x];
    __syncthreads();

    int w = threadIdx.x >> 6, lane = threadIdx.x & 63;
    int n = blockIdx.x * 4 + w;
    if (n >= N) return;

    int s = offs[n], e = offs[n + 1];
    int r = (lane < 60) ? lane : 0;
    int bq = r / 15, jp = r % 15;
    const uint* h32 = (const uint*)h;
    float a0 = 0.f, a1 = 0.f;
    int i = (lane < 60) ? s : e;           // lanes 60..63 idle in the loop

    int v0, v1, v2, v3, v4, v5, v6, v7;
    if (i + 7 < e) {                       // preload first group
        v0 = list[i];     v1 = list[i + 1]; v2 = list[i + 2]; v3 = list[i + 3];
        v4 = list[i + 4]; v5 = list[i + 5]; v6 = list[i + 6]; v7 = list[i + 7];
    }
    while (i + 7 < e) {
        int inext = i + 8;
        // prefetch next group's list entries (independent of this group's h loads)
        int nv0 = 0, nv1 = 0, nv2 = 0, nv3 = 0, nv4 = 0, nv5 = 0, nv6 = 0, nv7 = 0;
        bool hn = inext + 7 < e;
        if (hn) {
            nv0 = list[inext];     nv1 = list[inext + 1]; nv2 = list[inext + 2]; nv3 = list[inext + 3];
            nv4 = list[inext + 4]; nv5 = list[inext + 5]; nv6 = list[inext + 6]; nv7 = list[inext + 7];
        }
        uint d0 = h32[(size_t)(v0 & 0x7FFFFFFF) * 64 + bq * 16 + jp];
        uint d1 = h32[(size_t)(v1 & 0x7FFFFFFF) * 64 + bq * 16 + jp];
        uint d2 = h32[(size_t)(v2 & 0x7FFFFFFF) * 64 + bq * 16 + jp];
        uint d3 = h32[(size_t)(v3 & 0x7FFFFFFF) * 64 + bq * 16 + jp];
        uint d4 = h32[(size_t)(v4 & 0x7FFFFFFF) * 64 + bq * 16 + jp];
        uint d5 = h32[(size_t)(v5 & 0x7FFFFFFF) * 64 + bq * 16 + jp];
        uint d6 = h32[(size_t)(v6 & 0x7FFFFFFF) * 64 + bq * 16 + jp];
        uint d7 = h32[(size_t)(v7 & 0x7FFFFFFF) * 64 + bq * 16 + jp];
        float g0 = (v0 < 0) ? -1.f : 1.f, g1 = (v1 < 0) ? -1.f : 1.f;
        float g2 = (v2 < 0) ? -1.f : 1.f, g3 = (v3 < 0) ? -1.f : 1.f;
        float g4 = (v4 < 0) ? -1.f : 1.f, g5 = (v5 < 0) ? -1.f : 1.f;
        float g6 = (v6 < 0) ? -1.f : 1.f, g7 = (v7 < 0) ? -1.f : 1.f;
        a0 += g0 * bf2f((ushort)d0) + g1 * bf2f((ushort)d1)
            + g2 * bf2f((ushort)d2) + g3 * bf2f((ushort)d3)
            + g4 * bf2f((ushort)d4) + g5 * bf2f((ushort)d5)
            + g6 * bf2f((ushort)d6) + g7 * bf2f((ushort)d7);
        a1 += g0 * bf2f((ushort)(d0 >> 16)) + g1 * bf2f((ushort)(d1 >> 16))
            + g2 * bf2f((ushort)(d2 >> 16)) + g3 * bf2f((ushort)(d3 >> 16))
            + g4 * bf2f((ushort)(d4 >> 16)) + g5 * bf2f((ushort)(d5 >> 16))
            + g6 * bf2f((ushort)(d6 >> 16)) + g7 * bf2f((ushort)(d7 >> 16));
        i = inext;
        v0 = nv0; v1 = nv1; v2 = nv2; v3 = nv3;
        v4 = nv4; v5 = nv5; v6 = nv6; v7 = nv7;
    }
    for (; i + 3 < e; i += 4) {
        int u0 = list[i], u1 = list[i + 1], u2 = list[i + 2], u3 = list[i + 3];
        uint d0 = h32[(size_t)(u0 & 0x7FFFFFFF) * 64 + bq * 16 + jp];
        uint d1 = h32[(size_t)(u1 & 0x7FFFFFFF) * 64 + bq * 16 + jp];
        uint d2 = h32[(size_t)(u2 & 0x7FFFFFFF) * 64 + bq * 16 + jp];
        uint d3 = h32[(size_t)(u3 & 0x7FFFFFFF) * 64 + bq * 16 + jp];
        float g0 = (u0 < 0) ? -1.f : 1.f;
        float g1 = (u1 < 0) ? -1.f : 1.f;
        float g2 = (u2 < 0) ? -1.f : 1.f;
        float g3 = (u3 < 0) ? -1.f : 1.f;
        a0 += g0 * bf2f((ushort)d0) + g1 * bf2f((ushort)d1)
            + g2 * bf2f((ushort)d2) + g3 * bf2f((ushort)d3);
        a1 += g0 * bf2f((ushort)(d0 >> 16)) + g1 * bf2f((ushort)(d1 >> 16))
            + g2 * bf2f((ushort)(d2 >> 16)) + g3 * bf2f((ushort)(d3 >> 16));
    }
    for (; i < e; i++) {
        int v = list[i];
        uint d = h32[(size_t)(v & 0x7FFFFFFF) * 64 + bq * 16 + jp];
        float g = (v < 0) ? -1.f : 1.f;
        a0 += g * bf2f((ushort)d);
        a1 += g * bf2f((ushort)(d >> 16));
    }
    if (lane < 60) {
        sacc[w][bq][jp * 2]     = a0;
        sacc[w][bq][jp * 2 + 1] = a1;
    }
    int b = lane >> 4, k = lane & 15;
    float o0 = sb3[k], o1 = sb3[k + 16];
#pragma unroll
    for (int j = 0; j < H2_F; j++) {
        float v = sacc[w][b][j];
        o0 += v * sW3[j * 32 + k];
        o1 += v * sW3[j * 32 + k + 16];
    }
    float* op = out + ((size_t)b * N + n) * 32;
    op[k]      = sigmoidf_(o0);
    op[k + 16] = sigmoidf_(o1);
}

// ---------------------------------------------------------------------------
// FALLBACK tier (round-5 path): scatter list + list-indirect gather
// ---------------------------------------------------------------------------
__global__ void __launch_bounds__(256) scatter_kernel(const int* __restrict__ ei,
                                                      int* __restrict__ cursor,
                                                      int* __restrict__ list, int E, int N) {
    int e = blockIdx.x * 256 + threadIdx.x;
    if (e < E) {
        int tgt = ei[E + e];
        int p = atomicAdd(&cursor[tgt], 1);
        list[p] = e;
        int src = ei[e];
        int q = atomicAdd(&cursor[src], 1);
        list[q] = e | (int)0x80000000u;
    }
}

template<bool USE_XB>
__global__ void __launch_bounds__(256) edge_mlp_mfma2(
    const float* __restrict__ x, const ushort* __restrict__ xb,
    const int* __restrict__ ei, const float* __restrict__ ea,
    const float* __restrict__ W1, const float* __restrict__ b1,
    const float* __restrict__ W2, const float* __restrict__ b2,
    const float* __restrict__ sums, ushort* __restrict__ h,
    int E, int N, int tiles) {
    __shared__ ushort __attribute__((aligned(16))) hbuf[4][16 * 40];
    int w = threadIdx.x >> 6;
    int lane = threadIdx.x & 63;
    int n16 = lane & 15;
    int q = lane >> 4;

    Frag w1f[2][2];
#pragma unroll
    for (int t = 0; t < 2; t++)
#pragma unroll
        for (int s = 0; s < 2; s++)
#pragma unroll
            for (int j = 0; j < 4; j++) {
                int k0 = 32 * s + q * 8 + 2 * j;
                w1f[t][s].u[j] = pk2(W1[(size_t)k0 * 32 + 16 * t + n16],
                                     W1[(size_t)(k0 + 1) * 32 + 16 * t + n16]);
            }
    Frag w2f[2];
#pragma unroll
    for (int t = 0; t < 2; t++) {
        int m = 16 * t + n16;
#pragma unroll
        for (int j = 0; j < 4; j++) {
            int k0 = q * 8 + 2 * j;
            float a = (m < H2_F) ? W2[(size_t)k0 * H2_F + m] : 0.f;
            float d = (m < H2_F) ? W2[(size_t)(k0 + 1) * H2_F + m] : 0.f;
            w2f[t].u[j] = pk2(a, d);
        }
    }
    float b1q[2][4], w1Lq[2][4], b2q[2][4];
#pragma unroll
    for (int t = 0; t < 2; t++)
#pragma unroll
        for (int r = 0; r < 4; r++) {
            int col = 16 * t + q * 4 + r;
            b1q[t][r]  = b1[col];
            w1Lq[t][r] = W1[(size_t)64 * 32 + col];
            b2q[t][r]  = (col < H2_F) ? b2[col] : 0.f;
        }

    float mean = sums[0] / (float)E;
    float var = (sums[1] - (float)E * mean * mean) / (float)(E - 1);
    float istd = rsqrtf(var);

    int b = n16 & 3;
    int eoff = n16 >> 2;
    int gw = blockIdx.x * 4 + w;

    for (int tix = 0; tix < TPW; ++tix) {
        int tile = gw * TPW + tix;
        if (tile >= tiles) break;
        int e0 = tile * 4;
        int eA = e0 + eoff;
        bool vrow = eA < E;
        int eAc = vrow ? eA : E - 1;
        int src = ei[eAc], tgt = ei[E + eAc];
        float eav = (ea[eAc] - mean) * istd;

        Frag a0, a1;
        if (USE_XB) {
            *(uint4*)&a0.u[0] = *(const uint4*)(xb + ((size_t)b * N + src) * IN_F + q * 8);
            *(uint4*)&a1.u[0] = *(const uint4*)(xb + ((size_t)b * N + tgt) * IN_F + q * 8);
        } else {
            const float4* ps = (const float4*)(x + ((size_t)b * N + src) * IN_F + q * 8);
            float4 s0 = ps[0], s1 = ps[1];
            const float4* pt = (const float4*)(x + ((size_t)b * N + tgt) * IN_F + q * 8);
            float4 t0 = pt[0], t1 = pt[1];
            a0.u[0] = pk2(s0.x, s0.y); a0.u[1] = pk2(s0.z, s0.w);
            a0.u[2] = pk2(s1.x, s1.y); a0.u[3] = pk2(s1.z, s1.w);
            a1.u[0] = pk2(t0.x, t0.y); a1.u[1] = pk2(t0.z, t0.w);
            a1.u[2] = pk2(t1.x, t1.y); a1.u[3] = pk2(t1.z, t1.w);
        }

        f32x4 acc0, acc1;
#pragma unroll
        for (int r = 0; r < 4; r++) {
            acc0[r] = b1q[0][r] + eav * w1Lq[0][r];
            acc1[r] = b1q[1][r] + eav * w1Lq[1][r];
        }
        acc0 = __builtin_amdgcn_mfma_f32_16x16x32_bf16(w1f[0][0].v, a0.v, acc0, 0, 0, 0);
        acc0 = __builtin_amdgcn_mfma_f32_16x16x32_bf16(w1f[0][1].v, a1.v, acc0, 0, 0, 0);
        acc1 = __builtin_amdgcn_mfma_f32_16x16x32_bf16(w1f[1][0].v, a0.v, acc1, 0, 0, 0);
        acc1 = __builtin_amdgcn_mfma_f32_16x16x32_bf16(w1f[1][1].v, a1.v, acc1, 0, 0, 0);

        uint u0 = pk2(sigmoidf_(acc0[0]), sigmoidf_(acc0[1]));
        uint u1 = pk2(sigmoidf_(acc0[2]), sigmoidf_(acc0[3]));
        uint u2 = pk2(sigmoidf_(acc1[0]), sigmoidf_(acc1[1]));
        uint u3 = pk2(sigmoidf_(acc1[2]), sigmoidf_(acc1[3]));
        uint2 p01 = {u0, u1}, p23 = {u2, u3};
        *(uint2*)&hbuf[w][n16 * 40 + q * 4]      = p01;
        *(uint2*)&hbuf[w][n16 * 40 + 16 + q * 4] = p23;

        Frag ha;
        *(uint4*)&ha.u[0] = *(const uint4*)&hbuf[w][n16 * 40 + q * 8];

        f32x4 c0, c1;
#pragma unroll
        for (int r = 0; r < 4; r++) { c0[r] = b2q[0][r]; c1[r] = b2q[1][r]; }
        c0 = __builtin_amdgcn_mfma_f32_16x16x32_bf16(w2f[0].v, ha.v, c0, 0, 0, 0);
        c1 = __builtin_amdgcn_mfma_f32_16x16x32_bf16(w2f[1].v, ha.v, c1, 0, 0, 0);

        uint g0 = pk2(sigmoidf_(c0[0]), sigmoidf_(c0[1]));
        uint g1 = pk2(sigmoidf_(c0[2]), sigmoidf_(c0[3]));
        uint g2 = pk2(sigmoidf_(c1[0]), sigmoidf_(c1[1]));
        uint g3 = pk2(sigmoidf_(c1[2]), sigmoidf_(c1[3]));
        if (vrow) {
            uint* base = (uint*)(h + (size_t)(e0 * 4 + n16) * H2_F);
            base[q * 2]     = g0;
            base[q * 2 + 1] = g1;
            base[8 + q * 2] = g2;
            if (q < 3) base[8 + q * 2 + 1] = g3;
        }
    }
}

__global__ void __launch_bounds__(256) gather_final(
    const ushort* __restrict__ h, const int* __restrict__ list,
    const int* __restrict__ offs, const float* __restrict__ W3,
    const float* __restrict__ b3, float* __restrict__ out, int N) {
    __shared__ float sW3[H2_F * 32];
    __shared__ float sb3[32];
    __shared__ float sacc[4][B_SZ][H2_F];
    for (int i = threadIdx.x; i < H2_F * 32; i += 256) sW3[i] = W3[i];
    if (threadIdx.x < 32) sb3[threadIdx.x] = b3[threadIdx.x];
    __syncthreads();

    int w = threadIdx.x >> 6, lane = threadIdx.x & 63;
    int n = blockIdx.x * 4 + w;
    if (n >= N) return;

    if (lane < 60) {
        int bq = lane / 15, jp = lane % 15;
        float a0 = 0.f, a1 = 0.f;
        int s = offs[n], e = offs[n + 1];
        int i = s;
        for (; i + 4 <= e; i += 4) {
            int v0 = list[i], v1 = list[i + 1], v2 = list[i + 2], v3 = list[i + 3];
            uint d0 = *(const uint*)(h + (size_t)(v0 & 0x7FFFFFFF) * 120 + bq * 30 + jp * 2);
            uint d1 = *(const uint*)(h + (size_t)(v1 & 0x7FFFFFFF) * 120 + bq * 30 + jp * 2);
            uint d2 = *(const uint*)(h + (size_t)(v2 & 0x7FFFFFFF) * 120 + bq * 30 + jp * 2);
            uint d3 = *(const uint*)(h + (size_t)(v3 & 0x7FFFFFFF) * 120 + bq * 30 + jp * 2);
            float g0 = (v0 < 0) ? -1.f : 1.f;
            float g1 = (v1 < 0) ? -1.f : 1.f;
            float g2 = (v2 < 0) ? -1.f : 1.f;
            float g3 = (v3 < 0) ? -1.f : 1.f;
            a0 += g0 * bf2f((ushort)d0) + g1 * bf2f((ushort)d1)
                + g2 * bf2f((ushort)d2) + g3 * bf2f((ushort)d3);
            a1 += g0 * bf2f((ushort)(d0 >> 16)) + g1 * bf2f((ushort)(d1 >> 16))
                + g2 * bf2f((ushort)(d2 >> 16)) + g3 * bf2f((ushort)(d3 >> 16));
        }
        for (; i < e; i++) {
            int v = list[i];
            uint d = *(const uint*)(h + (size_t)(v & 0x7FFFFFFF) * 120 + bq * 30 + jp * 2);
            float g = (v < 0) ? -1.f : 1.f;
            a0 += g * bf2f((ushort)d);
            a1 += g * bf2f((ushort)(d >> 16));
        }
        sacc[w][bq][jp * 2]     = a0;
        sacc[w][bq][jp * 2 + 1] = a1;
    }
    int b = lane >> 4, k = lane & 15;
    float o0 = sb3[k], o1 = sb3[k + 16];
#pragma unroll
    for (int j = 0; j < H2_F; j++) {
        float v = sacc[w][b][j];
        o0 += v * sW3[j * 32 + k];
        o1 += v * sW3[j * 32 + k + 16];
    }
    float* op = out + ((size_t)b * N + n) * 32;
    op[k]      = sigmoidf_(o0);
    op[k + 16] = sigmoidf_(o1);
}

// ---------------------------------------------------------------------------
extern "C" void kernel_launch(void* const* d_in, const int* in_sizes, int n_in,
                              void* d_out, int out_size, void* d_ws, size_t ws_size,
                              hipStream_t stream) {
    const float* x  = (const float*)d_in[0];
    const int*   ei = (const int*)d_in[1];
    const float* ea = (const float*)d_in[2];
    const float* W1 = (const float*)d_in[3];
    const float* b1 = (const float*)d_in[4];
    const float* W2 = (const float*)d_in[5];
    const float* b2 = (const float*)d_in[6];
    const float* W3 = (const float*)d_in[7];
    const float* b3 = (const float*)d_in[8];
    float* out = (float*)d_out;

    const int E  = in_sizes[2];
    const int N  = in_sizes[0] / (B_SZ * IN_F);
    const int BN = B_SZ * N;
    const int nb = (N + 1023) / 1024;
    const long long n8 = (long long)BN * IN_F / 8;
    const int nblkC = (int)(((long long)E > n8 ? (long long)E : n8) + 255) / 256;

    char* base = (char*)d_ws;

    // ---- tier A: batch-major 16-edge tiles, e-indexed h (E x 256 B) + sign list ----
    size_t off = 0;
    int* cnt    = (int*)(base + off); off += (size_t)HREP * N * 4;  // replicated histogram
    float* sums = (float*)(base + off); off += 8;
    int* offs   = (int*)(base + off); off += (size_t)(N + 1) * 4;
    int* cursor = (int*)(base + off); off += (size_t)N * 4;
    int* bsum   = (int*)(base + off); off += 4096;
    off = (off + 255) & ~(size_t)255;
    float2* psums = (float2*)(base + off); off += (size_t)nblkC * 8;
    off = (off + 255) & ~(size_t)255;
    int* list   = (int*)(base + off); off += (size_t)2 * E * 4;
    off = (off + 255) & ~(size_t)255;
    ushort* h   = (ushort*)(base + off); off += (size_t)E * 256;
    off = (off + 255) & ~(size_t)255;
    ushort* xb  = (ushort*)(base + off); off += (size_t)BN * IN_F * 2;
    size_t needA = off;

    // ---- tier B (fallback): scatter list + e-indexed 120B h ----
    size_t offB = 0;
    int* cntB    = (int*)(base + offB); offB += (size_t)HREP * N * 4;
    float* sumsB = (float*)(base + offB); offB += 8;
    int* offsB   = (int*)(base + offB); offB += (size_t)(N + 1) * 4;
    int* cursorB = (int*)(base + offB); offB += (size_t)N * 4;
    int* bsumB   = (int*)(base + offB); offB += 4096;
    offB = (offB + 255) & ~(size_t)255;
    float2* psumsB = (float2*)(base + offB); offB += (size_t)nblkC * 8;
    int* listB   = (int*)(base + offB); offB += (size_t)2 * E * 4;
    offB = (offB + 255) & ~(size_t)255;
    ushort* hB   = (ushort*)(base + offB); offB += (size_t)E * 240;
    offB = (offB + 255) & ~(size_t)255;
    ushort* xbB  = (ushort*)(base + offB);
    size_t needB = offB + (size_t)BN * IN_F * 2;

    if (ws_size >= needA) {
        const int tiles = (E + 15) / 16;                 // 16 edges per tile, 1 batch
        const int wpb = (tiles + TPW - 1) / TPW;         // waves per batch
        const int bpb = (wpb + 3) / 4;                   // blocks per batch
        hipMemsetAsync(cnt, 0, (size_t)HREP * N * 4 + 8, stream);  // cnt replicas + sums
        stats_xcvt_kernel<<<nblkC, 256, 0, stream>>>(ea, ei, x, psums, cnt, xb, E, N, n8);
        sums_reduce_kernel<<<1, 256, 0, stream>>>(psums, sums, nblkC);
        scan1_kernel<<<nb, 256, 0, stream>>>(cnt, offs, bsum, N);
        scan2_kernel<<<1, 64, 0, stream>>>(bsum, offs, nb, N);
        scan3_kernel<<<nb, 256, 0, stream>>>(offs, cursor, bsum, N);
        // batch-major single pass: 4*bpb blocks, batch = blockIdx / bpb
        edge_mlp_e4<<<B_SZ * bpb, 256, 0, stream>>>(xb, ei, ea, W1, b1, W2, b2,
                                                    sums, cursor, list, h, E, N, tiles, bpb);
        gather_e4<<<(N + 3) / 4, 256, 0, stream>>>(h, list, offs, W3, b3, out, N);
    } else {
        const int tiles = (E + 3) / 4;
        const int waves = (tiles + TPW - 1) / TPW;
        const int eblocks = (waves + 3) / 4;
        bool use_xb = (ws_size >= needB);
        hipMemsetAsync(cntB, 0, (size_t)HREP * N * 4 + 8, stream);
        stats_xcvt_kernel<<<nblkC, 256, 0, stream>>>(ea, ei, x, psumsB, cntB,
                                                     use_xb ? xbB : (ushort*)nullptr,
                                                     E, N, use_xb ? n8 : 0LL);
        sums_reduce_kernel<<<1, 256, 0, stream>>>(psumsB, sumsB, nblkC);
        scan1_kernel<<<nb, 256, 0, stream>>>(cntB, offsB, bsumB, N);
        scan2_kernel<<<1, 64, 0, stream>>>(bsumB, offsB, nb, N);
        scan3_kernel<<<nb, 256, 0, stream>>>(offsB, cursorB, bsumB, N);
        scatter_kernel<<<(E + 255) / 256, 256, 0, stream>>>(ei, cursorB, listB, E, N);
        if (use_xb)
            edge_mlp_mfma2<true><<<eblocks, 256, 0, stream>>>(x, xbB, ei, ea, W1, b1,
                                                              W2, b2, sumsB, hB, E, N, tiles);
        else
            edge_mlp_mfma2<false><<<eblocks, 256, 0, stream>>>(x, xbB, ei, ea, W1, b1,
                                                               W2, b2, sumsB, hB, E, N, tiles);
        gather_final<<<(N + 3) / 4, 256, 0, stream>>>(hB, listB, offsB, W3, b3, out, N);
    }
}